// Round 3
// baseline (132.971 us; speedup 1.0000x reference)
//
#include <hip/hip_runtime.h>
#include <hip/hip_bf16.h>
#include <math.h>

// B=4, T=128, S=512, D=512. Outputs: attn_h (4,128,512) then align (4,128,512), fp32.
// 4-kernel pipeline (R8 = R7 with transposed-Eu, shuffle-free K2):
//   K1 fused_front (640): Ew=exp(2(inp@Wq^T+bq)), EuT[b][d][s]=exp(2*(Wc@ctx_b^T)),
//      GT[b]=(WL@ctx_b^T) bf16, Y0=inp@WR^T+bout
//   K2 align (1024): s across lanes, k sequential per lane -> ZERO cross-lane ops.
//      Sraw[b,t,s] = V - 2*sum_d v[d]/(1+Ew[t,d]*EuT[d,s]); paired rcp (1 rcp/2 d).
//   K3 softmax (512): alignv (fp32, d_out) + P_bf (bf16, ws)
//   K4 gemm_att (64): attn = P_bf @ GT^T + Y0   (MFMA, K=512)

typedef __attribute__((ext_vector_type(8))) short short8;
typedef __attribute__((ext_vector_type(4))) float f32x4;
typedef unsigned short ushort_t;

static __device__ __forceinline__ unsigned short f2bf(float x) {
    union { __hip_bfloat16 h; unsigned short u; } c;
    c.h = __float2bfloat16(x);
    return c.u;
}
static __device__ __forceinline__ int bf2x(float lo, float hi) {
    return (int)(((unsigned)f2bf(hi) << 16) | (unsigned)f2bf(lo));
}

template<bool BF>
static __device__ __forceinline__ void load16(const void* base, size_t elemoff,
                                              int4& r0, int4& r1) {
    if (BF) {
        const int4* p = (const int4*)((const ushort_t*)base + elemoff);
        r0 = p[0]; r1 = p[1];
    } else {
        const float4* p = (const float4*)((const float*)base + elemoff);
        float4 a = p[0], b = p[1], c = p[2], d = p[3];
        r0.x = bf2x(a.x, a.y); r0.y = bf2x(a.z, a.w);
        r0.z = bf2x(b.x, b.y); r0.w = bf2x(b.z, b.w);
        r1.x = bf2x(c.x, c.y); r1.y = bf2x(c.z, c.w);
        r1.z = bf2x(d.x, d.y); r1.w = bf2x(d.z, d.w);
    }
}

// ---------------------------------------------------------------------------
// MFMA NT GEMM tile: C[m,n] = sum_k A[m,k]*W[n,k] (+bias). 64x64 tile, BK=64,
// 256 thr = 4 waves (2x2 of 32x32), 2x2 MFMA 16x16x32 per 32-K step.
// LDS rows padded to 72 bf16 (<=2-way bank aliasing on b128 = free).
// EPI: 0 fp32+bias; 1 fp32 exp(2*(x+bias)); 2 bf16; 3 fp32 + partial[].
// ---------------------------------------------------------------------------
template<bool A_BF, bool W_BF, int EPI>
static __device__ __forceinline__ void gemm_body(
    ushort_t* As, ushort_t* Ws,
    const void* A, const void* W, const float* bias, const float* partial,
    void* Cv, int K, int lda, int ldw, int ldc, int bm, int bn)
{
    const int tid = threadIdx.x;
    const int wave = tid >> 6, lane = tid & 63;
    const int mh = (wave & 1) * 32, nh = (wave >> 1) * 32;
    const int quad = lane >> 4, l16 = lane & 15;
    const int srow = tid >> 2, schunk = tid & 3;

    const size_t aoff = (size_t)(bm + srow) * lda + schunk * 16;
    const size_t woff = (size_t)(bn + srow) * ldw + schunk * 16;
    int4* AsW = (int4*)&As[srow * 72 + schunk * 16];
    int4* WsW = (int4*)&Ws[srow * 72 + schunk * 16];

    f32x4 acc00 = {0.f, 0.f, 0.f, 0.f}, acc01 = acc00, acc10 = acc00, acc11 = acc00;

    int4 a0r, a1r, w0r, w1r;
    load16<A_BF>(A, aoff, a0r, a1r);
    load16<W_BF>(W, woff, w0r, w1r);

    for (int k0 = 0; k0 < K; k0 += 64) {
        AsW[0] = a0r; AsW[1] = a1r;
        WsW[0] = w0r; WsW[1] = w1r;
        __syncthreads();
        if (k0 + 64 < K) {
            load16<A_BF>(A, aoff + k0 + 64, a0r, a1r);
            load16<W_BF>(W, woff + k0 + 64, w0r, w1r);
        }
        #pragma unroll
        for (int kk = 0; kk < 64; kk += 32) {
            short8 a0 = *(const short8*)&As[(mh + l16) * 72 + kk + quad * 8];
            short8 a1 = *(const short8*)&As[(mh + 16 + l16) * 72 + kk + quad * 8];
            short8 b0 = *(const short8*)&Ws[(nh + l16) * 72 + kk + quad * 8];
            short8 b1 = *(const short8*)&Ws[(nh + 16 + l16) * 72 + kk + quad * 8];
            acc00 = __builtin_amdgcn_mfma_f32_16x16x32_bf16(a0, b0, acc00, 0, 0, 0);
            acc01 = __builtin_amdgcn_mfma_f32_16x16x32_bf16(a0, b1, acc01, 0, 0, 0);
            acc10 = __builtin_amdgcn_mfma_f32_16x16x32_bf16(a1, b0, acc10, 0, 0, 0);
            acc11 = __builtin_amdgcn_mfma_f32_16x16x32_bf16(a1, b1, acc11, 0, 0, 0);
        }
        __syncthreads();
    }

    const int col0 = bn + nh + l16;
    const int col1 = col0 + 16;
    float bias0 = bias ? bias[col0] : 0.f;
    float bias1 = bias ? bias[col1] : 0.f;

    f32x4 accs[2][2] = {{acc00, acc01}, {acc10, acc11}};
    #pragma unroll
    for (int mt = 0; mt < 2; ++mt) {
        #pragma unroll
        for (int r = 0; r < 4; ++r) {
            int row = bm + mh + mt * 16 + quad * 4 + r;
            size_t rowoff = (size_t)row * ldc;
            float v0 = accs[mt][0][r] + bias0;
            float v1 = accs[mt][1][r] + bias1;
            if (EPI == 1) { v0 = __expf(2.f * v0); v1 = __expf(2.f * v1); }
            if (EPI == 3) { v0 += partial[rowoff + col0]; v1 += partial[rowoff + col1]; }
            if (EPI == 2) {
                ushort_t* C = (ushort_t*)Cv;
                C[rowoff + col0] = f2bf(v0);
                C[rowoff + col1] = f2bf(v1);
            } else {
                float* C = (float*)Cv;
                C[rowoff + col0] = v0;
                C[rowoff + col1] = v1;
            }
        }
    }
}

// ---------------------------------------------------------------------------
// K1: fused front (640 GEMM blocks)
// [0,64)    Ew = exp(2*(inp@Wq^T + bq))            (row-major [t][d])
// [64,320)  EuT[b][e][s] = exp(2*sum_d Wc[e,d]*ctx[b][s,d])  (TRANSPOSED: d-major)
// [320,576) GT[b][n,s] = sum_d WL[n,d]*ctx[b][s,d]  (bf16)
// [576,640) Y0 = inp@WR^T + bout
// ---------------------------------------------------------------------------
__global__ __launch_bounds__(256) void fused_front(
    const float* __restrict__ inp, const float* __restrict__ ctx,
    const float* __restrict__ Wq, const float* __restrict__ bq,
    const float* __restrict__ Wc, const float* __restrict__ Wout,
    const float* __restrict__ bout,
    float* __restrict__ Ew, float* __restrict__ EuT, float* __restrict__ Y0,
    ushort_t* __restrict__ GT)
{
    __shared__ ushort_t As[64 * 72];
    __shared__ ushort_t Ws[64 * 72];
    const int bid = blockIdx.x;

    if (bid < 64) {
        gemm_body<false, false, 1>(As, Ws, inp, Wq, bq, nullptr, Ew,
                                   512, 512, 512, 512, (bid & 7) * 64, (bid >> 3) * 64);
    } else if (bid < 320) {
        int i = bid - 64;
        int b = i >> 6, j = i & 63;
        gemm_body<false, false, 1>(As, Ws, Wc, ctx + (size_t)b * 262144, nullptr,
                                   nullptr, EuT + (size_t)b * 262144,
                                   512, 512, 512, 512, (j & 7) * 64, (j >> 3) * 64);
    } else if (bid < 576) {
        int i = bid - 320;
        int b = i >> 6, j = i & 63;
        gemm_body<false, false, 2>(As, Ws, Wout, ctx + (size_t)b * 262144, nullptr,
                                   nullptr, GT + (size_t)b * 262144,
                                   512, 1024, 512, 512, (j & 7) * 64, (j >> 3) * 64);
    } else {
        int i = bid - 576;
        gemm_body<false, false, 0>(As, Ws, inp, Wout + 512, bout, nullptr, Y0,
                                   512, 512, 1024, 512, (i & 7) * 64, (i >> 3) * 64);
    }
}

// ---------------------------------------------------------------------------
// K2: Sraw[b,t,s] = V - 2*sum_d v[d]/(1 + Ew[b,t,d]*EuT[b,d,s]),  V = sum v[d]
// s across lanes (coalesced EuT/store), k SEQUENTIAL per lane -> no cross-lane
// reduction (the R7 kernel spent ~16 us/CU in 192 ds_swizzles per wave).
// Grid (8 s-groups, 32 t-groups, 4 b) = 1024 blocks, wave = 1 t x 64 s.
// Paired denominators kept: 1 rcp per 2 d-elements. 4 independent accs (ILP).
// ---------------------------------------------------------------------------
__global__ __launch_bounds__(256) void align_kernel(
    const float* __restrict__ Ew, const float* __restrict__ EuT,
    const float* __restrict__ v, float* __restrict__ out)
{
    const int lane = threadIdx.x & 63, wave = threadIdx.x >> 6;
    const int b = blockIdx.z;
    const int t = blockIdx.y * 4 + wave;
    const int s = blockIdx.x * 64 + lane;

    const float* wp = Ew + (((size_t)(b * 128 + t)) << 9);
    const float* up = EuT + ((size_t)b << 18) + s;

    // V = sum_d v[d]: 8 loads + 6 shuffles per wave (one-time, negligible)
    float vv = 0.f;
    #pragma unroll
    for (int i = 0; i < 8; ++i) vv += v[lane + 64 * i];
    #pragma unroll
    for (int off = 32; off; off >>= 1) vv += __shfl_xor(vv, off, 64);

    float acc0 = 0.f, acc1 = 0.f, acc2 = 0.f, acc3 = 0.f;

    for (int k0 = 0; k0 < 512; k0 += 8) {
        float w_[8], v_[8], u_[8];
        #pragma unroll
        for (int i = 0; i < 8; ++i) {
            w_[i] = wp[k0 + i];                       // lane-uniform -> SMEM
            v_[i] = v[k0 + i];                        // lane-uniform -> SMEM
            u_[i] = up[(size_t)(k0 + i) << 9];        // coalesced 256B/wave
        }
        float A0 = fmaf(w_[0], u_[0], 1.f);
        float B0 = fmaf(w_[1], u_[1], 1.f);
        float n0 = fmaf(v_[0], B0, v_[1] * A0);
        acc0 = fmaf(n0, __builtin_amdgcn_rcpf(A0 * B0), acc0);

        float A1 = fmaf(w_[2], u_[2], 1.f);
        float B1 = fmaf(w_[3], u_[3], 1.f);
        float n1 = fmaf(v_[2], B1, v_[3] * A1);
        acc1 = fmaf(n1, __builtin_amdgcn_rcpf(A1 * B1), acc1);

        float A2 = fmaf(w_[4], u_[4], 1.f);
        float B2 = fmaf(w_[5], u_[5], 1.f);
        float n2 = fmaf(v_[4], B2, v_[5] * A2);
        acc2 = fmaf(n2, __builtin_amdgcn_rcpf(A2 * B2), acc2);

        float A3 = fmaf(w_[6], u_[6], 1.f);
        float B3 = fmaf(w_[7], u_[7], 1.f);
        float n3 = fmaf(v_[6], B3, v_[7] * A3);
        acc3 = fmaf(n3, __builtin_amdgcn_rcpf(A3 * B3), acc3);
    }

    float acc = (acc0 + acc1) + (acc2 + acc3);
    out[(((size_t)(b * 128 + t)) << 9) + s] = fmaf(-2.f, acc, vv);
}

// ---------------------------------------------------------------------------
// K3: softmax over rows of 512. Reads Sraw, writes fp32 alignv + bf16 P.
// ---------------------------------------------------------------------------
__global__ __launch_bounds__(256) void softmax_512(
    const float* __restrict__ Sraw, float* __restrict__ alignv,
    ushort_t* __restrict__ pbf)
{
    const int row = blockIdx.x;
    const float* p = Sraw + ((size_t)row << 9);
    float* a = alignv + ((size_t)row << 9);
    ushort_t* q = pbf + ((size_t)row << 9);
    const int tid = threadIdx.x;
    float x0 = p[tid];
    float x1 = p[tid + 256];

    float m = fmaxf(x0, x1);
    #pragma unroll
    for (int off = 32; off > 0; off >>= 1)
        m = fmaxf(m, __shfl_xor(m, off, 64));
    __shared__ float redm[4];
    __shared__ float reds[4];
    const int wave = tid >> 6;
    if ((tid & 63) == 0) redm[wave] = m;
    __syncthreads();
    m = fmaxf(fmaxf(redm[0], redm[1]), fmaxf(redm[2], redm[3]));

    float e0 = __expf(x0 - m);
    float e1 = __expf(x1 - m);
    float s = e0 + e1;
    #pragma unroll
    for (int off = 32; off > 0; off >>= 1)
        s += __shfl_xor(s, off, 64);
    if ((tid & 63) == 0) reds[wave] = s;
    __syncthreads();
    s = reds[0] + reds[1] + reds[2] + reds[3];
    float r = 1.0f / s;
    float p0 = e0 * r, p1 = e1 * r;
    a[tid] = p0;
    a[tid + 256] = p1;
    q[tid] = f2bf(p0);
    q[tid + 256] = f2bf(p1);
}

// ---------------------------------------------------------------------------
// K4: attn = P_bf @ GT^T + Y0. Per-batch M=128, N=512, K=512. Grid (2,8,4).
// ---------------------------------------------------------------------------
__global__ __launch_bounds__(256) void gemm_att(
    const ushort_t* __restrict__ P, const ushort_t* __restrict__ GT,
    const float* __restrict__ Y0, float* __restrict__ attn)
{
    __shared__ ushort_t As[64 * 72];
    __shared__ ushort_t Ws[64 * 72];
    const int b = blockIdx.z;
    gemm_body<true, true, 3>(As, Ws,
                             P + (size_t)b * 65536, GT + (size_t)b * 262144,
                             nullptr, Y0 + (size_t)b * 65536,
                             attn + (size_t)b * 65536,
                             512, 512, 512, 512, blockIdx.x * 64, blockIdx.y * 64);
}

// ---------------------------------------------------------------------------
extern "C" void kernel_launch(void* const* d_in, const int* in_sizes, int n_in,
                              void* d_out, int out_size, void* d_ws, size_t ws_size,
                              hipStream_t stream)
{
    const float* inp  = (const float*)d_in[0];   // (4,128,512)
    const float* ctx  = (const float*)d_in[1];   // (4,512,512)
    const float* Wq   = (const float*)d_in[2];   // (512,512)
    const float* bq   = (const float*)d_in[3];   // (512)
    const float* Wc   = (const float*)d_in[4];   // (512,512)
    const float* v    = (const float*)d_in[5];   // (512)
    const float* Wout = (const float*)d_in[6];   // (512,1024)
    const float* bout = (const float*)d_in[7];   // (512)

    float* out    = (float*)d_out;
    float* attn   = out;              // 262144 floats
    float* alignv = out + 262144;     // 262144 floats

    float* ws = (float*)d_ws;
    float* Ew   = ws;                          // 262144 f
    float* EuT  = ws + 262144;                 // 1048576 f  (transposed: [b][d][s])
    float* Y0   = ws + 1310720;                // 262144 f
    float* Sraw = ws + 1572864;                // 262144 f
    ushort_t* GT   = (ushort_t*)(ws + 1835008); // 1048576 u16 (= 524288 f)
    ushort_t* P_bf = (ushort_t*)(ws + 2359296); // 262144 u16

    fused_front<<<dim3(640), 256, 0, stream>>>(inp, ctx, Wq, bq, Wc, Wout, bout,
                                               Ew, EuT, Y0, GT);
    align_kernel<<<dim3(8, 32, 4), 256, 0, stream>>>(Ew, EuT, v, Sraw);
    softmax_512<<<dim3(512), 256, 0, stream>>>(Sraw, alignv, P_bf);
    gemm_att<<<dim3(2, 8, 4), 256, 0, stream>>>(P_bf, GT, Y0, attn);
}